// Round 5
// baseline (1785.453 us; speedup 1.0000x reference)
//
#include <hip/hip_runtime.h>

// HODLR matvec, round 5 (= round-4 design, compile fix: s_sleep const args).
// Fused single-launch, NO grid barriers.
// Per-wg 3-deep level pipeline with event flags (64 distributed lines/event):
//   iter j:  stage u_j -> LDS ; proj_j (arrive P_j)
//            red1_{j-1} (wait P_{j-1})  [levels 0-2 two-stage via s1-alias]
//            red2_{j-2} (wait R1)       [levels 0-2 only]
//            exp_{j-2}  (wait R2_{j-2}; u read from GLOBAL = LLC-hit at lag 2)
// u streamed from HBM exactly once; exp's u re-read is LLC-served.
// s1 scratch aliases into ts slices of levels 7/6/5 (disjoint by skew bound).
// Fallback to the proven 3-kernel path (464 us) if cooperative launch fails.

typedef __attribute__((ext_vector_type(8))) short bf16x8;
typedef __attribute__((ext_vector_type(4))) float f32x4;

constexpr int BATCH = 64;
constexpr int NN    = 262144;   // 2^18 nodes
constexpr int RANK  = 64;
constexpr int DEPTH = 8;
constexpr int CHUNK = 256;
constexpr int NCHUNK = NN / CHUNK;      // 1024
constexpr int NWG  = NCHUNK;
constexpr int NTHR = 256;
constexpr int LSTR  = 264;      // legacy fallback stride
constexpr int WIN   = 256;      // legacy fallback window
constexpr size_t TS_FLOATS = 510ull * 4096;   // 8,355,840 B of ts

// event ids: P_L = 0..7 (proj done), R1_L = 8..10 (red stage1, L<=2),
// R2_L = 11..18 (ts level L complete)
constexpr int EV_P  = 0;
constexpr int EV_R1 = 8;
constexpr int EV_R2 = 11;
constexpr int NEV   = 19;
constexpr int FLINE = 32;       // dwords per flag line (128 B)

__device__ __forceinline__ short f2bf(float f) {
  union { float f; unsigned u; } v; v.f = f;
  unsigned r = v.u + 0x7FFFu + ((v.u >> 16) & 1u);   // round-to-nearest-even
  return (short)(r >> 16);
}

__device__ __forceinline__ float bf2f(short s) {
  union { unsigned u; float f; } v; v.u = ((unsigned)(unsigned short)s) << 16;
  return v.f;
}

__device__ __forceinline__ bf16x8 pack8(f32x4 a, f32x4 b) {
  bf16x8 f;
  f[0] = f2bf(a[0]); f[1] = f2bf(a[1]); f[2] = f2bf(a[2]); f[3] = f2bf(a[3]);
  f[4] = f2bf(b[0]); f[5] = f2bf(b[1]); f[6] = f2bf(b[2]); f[7] = f2bf(b[3]);
  return f;
}

// agent-scope (XCD-L2-bypassing) access helpers
__device__ __forceinline__ unsigned short aload_u16(const unsigned short* p) {
  return __hip_atomic_load(p, __ATOMIC_RELAXED, __HIP_MEMORY_SCOPE_AGENT);
}
__device__ __forceinline__ float aload_f32(const float* p) {
  return __hip_atomic_load(p, __ATOMIC_RELAXED, __HIP_MEMORY_SCOPE_AGENT);
}
__device__ __forceinline__ void astore_u16(unsigned short* p, unsigned short v) {
  __hip_atomic_store(p, v, __ATOMIC_RELAXED, __HIP_MEMORY_SCOPE_AGENT);
}
__device__ __forceinline__ void astore_f32(float* p, float v) {
  __hip_atomic_store(p, v, __ATOMIC_RELAXED, __HIP_MEMORY_SCOPE_AGENT);
}

// LDS row offset for transposed u-tile ulds[r][c] (shorts): rows 16B-aligned
// (b128 legal for proj), 8-row stride = 4 mod 32 banks (proj reads conflict-lite).
__device__ __forceinline__ int rowoff(int r) { return r * 264 + ((r >> 3) << 3); }

// ---- event flags: arrive once per wg (release), wait = 64 lanes poll ----
__device__ __forceinline__ void arrive_ev(unsigned* flags, int ev) {
  __syncthreads();   // all wg threads' agent stores drained (vmcnt) first
  if (threadIdx.x == 0)
    __hip_atomic_fetch_add(flags + (ev * 64 + (blockIdx.x & 63)) * FLINE, 1u,
                           __ATOMIC_RELEASE, __HIP_MEMORY_SCOPE_AGENT);
}
__device__ __forceinline__ void wait_ev(unsigned* flags, int ev) {
  if (threadIdx.x < 64) {
    const unsigned* a = flags + (ev * 64 + threadIdx.x) * FLINE;
    int it = 0;
    while (__hip_atomic_load(a, __ATOMIC_ACQUIRE, __HIP_MEMORY_SCOPE_AGENT) < 16u) {
      if (it < 16) __builtin_amdgcn_s_sleep(2);
      else         __builtin_amdgcn_s_sleep(8);
      ++it;
    }
  }
  __syncthreads();
}

__global__ __launch_bounds__(256, 4) void k_fused4(
    const float* __restrict__ x, const float* __restrict__ diag,
    const float* __restrict__ u, float* y,
    short* part, float* ts, unsigned* flags)
{
  __shared__ alignas(16) short ulds[64 * 264 + 64];   // 33,920 B -> 4 wg/CU

  const int c0   = blockIdx.x * CHUNK;
  const int tid  = threadIdx.x;
  const int w    = tid >> 6;
  const int lane = tid & 63;
  const int lg   = lane >> 4;
  const int lr   = lane & 15;
  const int bw   = 16 * w;
  const int T    = blockIdx.x * NTHR + tid;

  // x A-fragments (bf16), resident for all levels
  bf16x8 xf[CHUNK / 32];
  {
    const float* xp = x + (size_t)(bw + lr) * NN + c0 + lg * 8;
    #pragma unroll
    for (int s = 0; s < CHUNK / 32; ++s) {
      f32x4 a = *(const f32x4*)(xp + s * 32);
      f32x4 b = *(const f32x4*)(xp + s * 32 + 4);
      xf[s] = pack8(a, b);
    }
  }

  f32x4 yacc[16];
  #pragma unroll
  for (int ct = 0; ct < 16; ++ct) yacc[ct] = (f32x4){0.f, 0.f, 0.f, 0.f};

  #pragma unroll 1
  for (int j = 0; j < DEPTH + 2; ++j) {

    // ---- phase 1+2: stage u_j into LDS, proj_j, arrive P_j ----
    if (j < DEPTH) {
      __syncthreads();   // proj_{j-1} finished reading ulds
      {
        const float* ug = u + ((size_t)j * NN + c0 + tid) * RANK;
        #pragma unroll
        for (int h = 0; h < 4; ++h) {
          f32x4 t[4];
          #pragma unroll
          for (int q = 0; q < 4; ++q) t[q] = *(const f32x4*)(ug + h * 16 + q * 4);
          #pragma unroll
          for (int q = 0; q < 4; ++q) {
            #pragma unroll
            for (int e = 0; e < 4; ++e) {
              const int r = h * 16 + q * 4 + e;
              ulds[rowoff(r) + tid] = f2bf(t[q][e]);
            }
          }
        }
      }
      __syncthreads();

      {
        unsigned short* pb = (unsigned short*)(part +
            ((size_t)j * NCHUNK + blockIdx.x) * (BATCH * RANK));
        #pragma unroll
        for (int rt = 0; rt < 4; ++rt) {
          f32x4 pacc = (f32x4){0.f, 0.f, 0.f, 0.f};
          const int rbase = rowoff(rt * 16 + lr);
          #pragma unroll
          for (int s = 0; s < CHUNK / 32; ++s) {
            bf16x8 bf = *(const bf16x8*)&ulds[rbase + s * 32 + lg * 8];
            pacc = __builtin_amdgcn_mfma_f32_16x16x32_bf16(xf[s], bf, pacc, 0, 0, 0);
          }
          #pragma unroll
          for (int v = 0; v < 4; ++v)          // D: row = lg*4+v, col = lr
            astore_u16(pb + (bw + lg * 4 + v) * RANK + rt * 16 + lr,
                       (unsigned short)f2bf(pacc[v]));
        }
      }
      arrive_ev(flags, EV_P + j);
    }

    // ---- phase 3: reduce (stage 1 / full) for level L = j-1 ----
    {
      const int L = j - 1;
      if (L >= 0 && L < DEPTH) {
        wait_ev(flags, EV_P + L);
        const int contrib = 512 >> L;
        const int tsbase  = ((1 << (L + 1)) - 2) * (BATCH * RANK);
        const unsigned short* pl = (const unsigned short*)(part +
            (size_t)L * NCHUNK * (BATCH * RANK));
        if (L <= 2) {
          // stage 1: every thread sums 16 chunk-partials of one (grp, e);
          // s1 aliased into the (unwritten) ts slice of level 7-L.
          float* s1 = ts + ((size_t)(1 << (8 - L)) - 2) * (BATCH * RANK);
          const int entries = 1 << (13 + L);   // 8192, 16384, 32768
          const int e   = T & (entries - 1);
          const int grp = T >> (13 + L);
          const int blk = e >> 12, br = e & 4095;
          const unsigned short* p = pl + (size_t)(blk * contrib + grp * 16) * 4096 + br;
          float s = 0.f;
          #pragma unroll
          for (int k = 0; k < 16; ++k) s += bf2f((short)aload_u16(p + (size_t)k * 4096));
          astore_f32(&s1[(size_t)grp * entries + e], s);
          arrive_ev(flags, EV_R1 + L);
        } else if (L <= 4) {
          // one thread per entry, contrib = 64 / 32 loads
          const int entries = 1 << (13 + L);   // 65536, 131072
          if (T < entries) {
            const int blk = T >> 12, br = T & 4095;
            const unsigned short* p = pl + (size_t)(blk * contrib) * 4096 + br;
            float s = 0.f;
            for (int k0 = 0; k0 < contrib; k0 += 16) {
              #pragma unroll
              for (int k = 0; k < 16; ++k)
                s += bf2f((short)aload_u16(p + (size_t)(k0 + k) * 4096));
            }
            astore_f32(&ts[tsbase + T], s);
          }
          arrive_ev(flags, EV_R2 + L);
        } else {
          const int units = 1 << (L - 5);      // 1, 2, 4
          for (int uu = 0; uu < units; ++uu) {
            const int e = T + (uu << 18);
            const int blk = e >> 12, br = e & 4095;
            const unsigned short* p = pl + (size_t)(blk * contrib) * 4096 + br;
            float s = 0.f;
            #pragma unroll
            for (int k = 0; k < 16; ++k)
              if (k < contrib) s += bf2f((short)aload_u16(p + (size_t)k * 4096));
            astore_f32(&ts[tsbase + e], s);
          }
          arrive_ev(flags, EV_R2 + L);
        }
      }
    }

    // ---- phase 4: reduce stage 2 for level L2 = j-2 (levels 0-2 only) ----
    {
      const int L2 = j - 2;
      if (L2 >= 0 && L2 <= 2) {
        wait_ev(flags, EV_R1 + L2);
        const float* s1 = ts + ((size_t)(1 << (8 - L2)) - 2) * (BATCH * RANK);
        const int tsbase  = ((1 << (L2 + 1)) - 2) * (BATCH * RANK);
        const int entries = 1 << (13 + L2);
        const int G       = 32 >> L2;          // 32, 16, 8
        if (T < entries) {
          float s2 = 0.f;
          #pragma unroll 8
          for (int g2 = 0; g2 < G; ++g2)
            s2 += aload_f32(&s1[(size_t)g2 * entries + T]);
          astore_f32(&ts[tsbase + T], s2);
        }
        arrive_ev(flags, EV_R2 + L2);
      }
    }

    // ---- phase 5: exp level L2 = j-2, u read from GLOBAL (LLC-hit) ----
    {
      const int L2 = j - 2;
      if (L2 >= 0 && L2 < DEPTH) {
        wait_ev(flags, EV_R2 + L2);
        const int blk = c0 >> (17 - L2);
        const float* tb = ts + (size_t)(((1 << (L2 + 1)) - 2) + (blk ^ 1)) * (BATCH * RANK);

        bf16x8 af[2];
        #pragma unroll
        for (int s2 = 0; s2 < 2; ++s2) {
          const float* p = tb + (size_t)(bw + lr) * RANK + s2 * 32 + lg * 8;
          f32x4 a, b;
          #pragma unroll
          for (int jj = 0; jj < 4; ++jj) {
            a[jj] = aload_f32(p + jj);
            b[jj] = aload_f32(p + 4 + jj);
          }
          af[s2] = pack8(a, b);
        }

        const float* ub = u + ((size_t)L2 * NN + c0) * RANK;
        #pragma unroll
        for (int ct = 0; ct < 16; ++ct) {
          const float* up = ub + (size_t)(ct * 16 + lr) * RANK + lg * 8;
          #pragma unroll
          for (int s2 = 0; s2 < 2; ++s2) {
            f32x4 a = *(const f32x4*)(up + s2 * 32);
            f32x4 b = *(const f32x4*)(up + s2 * 32 + 4);
            yacc[ct] = __builtin_amdgcn_mfma_f32_16x16x32_bf16(af[s2], pack8(a, b),
                                                               yacc[ct], 0, 0, 0);
          }
        }
      }
    }
  }

  // ---- epilogue: y = yacc + diag*x ----
  // part/y alias safe: last part read (red_7) precedes EV_R2_7, which exp_7
  // (and thus this epilogue) waits on.
  #pragma unroll
  for (int ct = 0; ct < 16; ++ct) {
    const int c = c0 + ct * 16 + lr;
    const float dg = diag[c];
    #pragma unroll
    for (int v = 0; v < 4; ++v) {
      const int b = bw + lg * 4 + v;
      const size_t idx = (size_t)b * NN + c;
      y[idx] = yacc[ct][v] + dg * x[idx];
    }
  }
}

// ================= legacy 3-kernel path (fallback only, proven 464 us) ======

__global__ __launch_bounds__(256, 4) void k_proj2(
    const float* __restrict__ x, const float* __restrict__ u,
    short* __restrict__ part)
{
  __shared__ alignas(16) short ulds[RANK * LSTR];

  const int c0   = blockIdx.x * CHUNK;
  const int tid  = threadIdx.x;
  const int w    = tid >> 6;
  const int lane = tid & 63;
  const int lg   = lane >> 4;
  const int lr   = lane & 15;

  bf16x8 xf[CHUNK / 32];
  {
    const float* xp = x + (size_t)(16 * w + lr) * NN + c0 + lg * 8;
    #pragma unroll
    for (int s = 0; s < CHUNK / 32; ++s) {
      f32x4 a = *(const f32x4*)(xp + s * 32);
      f32x4 b = *(const f32x4*)(xp + s * 32 + 4);
      xf[s] = pack8(a, b);
    }
  }

  for (int i = 0; i < DEPTH; ++i) {
    __syncthreads();
    {
      const float* ug = u + ((size_t)i * NN + c0 + tid) * RANK;
      short* col = &ulds[tid];
      #pragma unroll
      for (int h = 0; h < 2; ++h) {
        f32x4 t[8];
        #pragma unroll
        for (int q = 0; q < 8; ++q) t[q] = *(const f32x4*)(ug + h * 32 + q * 4);
        #pragma unroll
        for (int q = 0; q < 8; ++q) {
          #pragma unroll
          for (int e = 0; e < 4; ++e)
            col[(h * 32 + q * 4 + e) * LSTR] = f2bf(t[q][e]);
        }
      }
    }
    __syncthreads();

    f32x4 pacc[4];
    #pragma unroll
    for (int rt = 0; rt < 4; ++rt) pacc[rt] = (f32x4){0.f, 0.f, 0.f, 0.f};
    #pragma unroll
    for (int s = 0; s < CHUNK / 32; ++s) {
      #pragma unroll
      for (int rt = 0; rt < 4; ++rt) {
        bf16x8 bf = *(const bf16x8*)&ulds[(rt * 16 + lr) * LSTR + s * 32 + lg * 8];
        pacc[rt] = __builtin_amdgcn_mfma_f32_16x16x32_bf16(xf[s], bf, pacc[rt], 0, 0, 0);
      }
    }

    short* pb = part + ((size_t)i * NCHUNK + blockIdx.x) * (BATCH * RANK);
    #pragma unroll
    for (int rt = 0; rt < 4; ++rt) {
      #pragma unroll
      for (int v = 0; v < 4; ++v) {
        const int b = 16 * w + lg * 4 + v;
        pb[b * RANK + rt * 16 + lr] = f2bf(pacc[rt][v]);
      }
    }
  }
}

__global__ __launch_bounds__(256, 4) void k_reduce(
    const short* __restrict__ part, float* __restrict__ ts)
{
  int g = blockIdx.x;
  int lvl = 0;
  while (g >= ((2 << lvl) * 16)) { g -= (2 << lvl) * 16; ++lvl; }
  const int block = g >> 4;
  const int bq = (g >> 2) & 3;
  const int rq = g & 3;
  const int contrib = 512 >> lvl;
  const int chunk0  = block * contrib;

  const int b = bq * 16 + (threadIdx.x >> 4);
  const int r = rq * 16 + (threadIdx.x & 15);

  const short* p = part + ((size_t)lvl * NCHUNK + chunk0) * (BATCH * RANK) + b * RANK + r;
  float s = 0.f;
  int k = 0;
  for (; k + 8 <= contrib; k += 8) {
    float a0 = bf2f(p[(size_t)(k + 0) * 4096]);
    float a1 = bf2f(p[(size_t)(k + 1) * 4096]);
    float a2 = bf2f(p[(size_t)(k + 2) * 4096]);
    float a3 = bf2f(p[(size_t)(k + 3) * 4096]);
    float a4 = bf2f(p[(size_t)(k + 4) * 4096]);
    float a5 = bf2f(p[(size_t)(k + 5) * 4096]);
    float a6 = bf2f(p[(size_t)(k + 6) * 4096]);
    float a7 = bf2f(p[(size_t)(k + 7) * 4096]);
    s += ((a0 + a1) + (a2 + a3)) + ((a4 + a5) + (a6 + a7));
  }
  for (; k < contrib; ++k) s += bf2f(p[(size_t)k * 4096]);

  const int off = (1 << (lvl + 1)) - 2;
  ts[(size_t)(off + block) * (BATCH * RANK) + b * RANK + r] = s;
}

__global__ __launch_bounds__(256, 4) void k_exp2(
    const float* __restrict__ x, const float* __restrict__ diag,
    const float* __restrict__ u, const float* __restrict__ ts,
    float* __restrict__ y)
{
  const int cw0  = blockIdx.x * WIN;
  const int tid  = threadIdx.x;
  const int w    = tid >> 6;
  const int lane = tid & 63;
  const int lg   = lane >> 4;
  const int lr   = lane & 15;
  const int bw   = 16 * w;

  f32x4 yacc[16];
  #pragma unroll
  for (int ct = 0; ct < 16; ++ct) yacc[ct] = (f32x4){0.f, 0.f, 0.f, 0.f};

  #pragma unroll
  for (int i = 0; i < DEPTH; ++i) {
    const int blk = cw0 >> (17 - i);
    const int off = (1 << (i + 1)) - 2;
    const float* tb = ts + (size_t)(off + (blk ^ 1)) * (BATCH * RANK);

    bf16x8 af[2];
    #pragma unroll
    for (int s2 = 0; s2 < 2; ++s2) {
      const float* p = tb + (size_t)(bw + lr) * RANK + s2 * 32 + lg * 8;
      af[s2] = pack8(*(const f32x4*)p, *(const f32x4*)(p + 4));
    }

    const float* ub = u + ((size_t)i * NN + cw0) * RANK;
    #pragma unroll
    for (int ct = 0; ct < 16; ++ct) {
      const float* up = ub + (size_t)(ct * 16 + lr) * RANK + lg * 8;
      #pragma unroll
      for (int s2 = 0; s2 < 2; ++s2) {
        f32x4 a = *(const f32x4*)(up + s2 * 32);
        f32x4 b = *(const f32x4*)(up + s2 * 32 + 4);
        yacc[ct] = __builtin_amdgcn_mfma_f32_16x16x32_bf16(af[s2], pack8(a, b), yacc[ct], 0, 0, 0);
      }
    }
  }

  #pragma unroll
  for (int ct = 0; ct < 16; ++ct) {
    const int c = cw0 + ct * 16 + lr;
    const float dg = diag[c];
    #pragma unroll
    for (int v = 0; v < 4; ++v) {
      const int b = bw + lg * 4 + v;
      const size_t idx = (size_t)b * NN + c;
      y[idx] = yacc[ct][v] + dg * x[idx];
    }
  }
}

extern "C" void kernel_launch(void* const* d_in, const int* in_sizes, int n_in,
                              void* d_out, int out_size, void* d_ws, size_t ws_size,
                              hipStream_t stream) {
  (void)in_sizes; (void)n_in; (void)out_size; (void)ws_size;
  const float* x    = (const float*)d_in[0];
  const float* diag = (const float*)d_in[1];
  const float* u    = (const float*)d_in[2];
  float* y    = (float*)d_out;
  short* part = (short*)d_out;          // d_out doubles as partial scratch
  float* ts   = (float*)d_ws;

  // ws layout: ts (8,355,840 B) | flags (19 events * 64 lines * 128 B = 155,648 B)
  char* wsb = (char*)d_ws;
  unsigned* flags = (unsigned*)(wsb + TS_FLOATS * 4);

  // zero only the flag region (ts fully overwritten; s1 aliases inside ts)
  (void)hipMemsetAsync(wsb + TS_FLOATS * 4, 0, (size_t)NEV * 64 * FLINE * 4, stream);

  void* args[7] = {(void*)&x, (void*)&diag, (void*)&u, (void*)&y,
                   (void*)&part, (void*)&ts, (void*)&flags};
  if (hipLaunchCooperativeKernel((const void*)k_fused4, dim3(NWG), dim3(NTHR),
                                 args, 0, stream) != hipSuccess) {
    // fallback: proven three-launch path (464 us baseline)
    k_proj2 <<<NCHUNK, 256, 0, stream>>>(x, u, part);
    k_reduce<<<8160,   256, 0, stream>>>(part, ts);
    k_exp2  <<<NN / WIN, 256, 0, stream>>>(x, diag, u, ts, y);
  }
}

// Round 6
// 705.666 us; speedup vs baseline: 2.5302x; 2.5302x over previous
//
#include <hip/hip_runtime.h>

// HODLR matvec, round 6: per-level multi-launch, LLC-mediated u reuse.
//   P0   : pack x->bf16 (xb), yws = diag*x, stage u0, proj0 -> part
//   per L: RED_L (part -> ts, plain stores, 2-stage for L<=2)
//          PE_L  = stage u_{L+1} (HBM) ; exp_L (u_L from LLC) ; yws += ; proj_{L+1}
//   EF   : exp7 + y = yws + acc
// Kernel boundaries are the sync (~2us each). u streamed from HBM once;
// exp's u re-read is LLC-served (u_L + u_{L+1} + yws + xb ~ 251 MB < 256 MB LLC).
// No atomics, no cooperative launch, no memset, no agent-scope ops.
// Fallback to the proven 3-kernel path if ws is too small.

typedef __attribute__((ext_vector_type(8))) short bf16x8;
typedef __attribute__((ext_vector_type(4))) float f32x4;

constexpr int BATCH = 64;
constexpr int NN    = 262144;   // 2^18 nodes
constexpr int RANK  = 64;
constexpr int DEPTH = 8;
constexpr int CHUNK = 256;
constexpr int NCHUNK = NN / CHUNK;      // 1024
constexpr int NTHR = 256;
constexpr int LSTR  = 264;      // legacy fallback stride
constexpr int WIN   = 256;      // legacy fallback window

// ws layout (bytes)
constexpr size_t YWS_OFF  = 0;                          // 64*262144*4 = 67,108,864
constexpr size_t XB_OFF   = 67108864;                   // 64*262144*2 = 33,554,432
constexpr size_t PART_OFF = XB_OFF + 33554432;          // 1024*4096*2 =  8,388,608
constexpr size_t TS_OFF   = PART_OFF + 8388608;         // 510*4096*4  =  8,355,840
constexpr size_t S1_OFF   = TS_OFF + 8355840;           // 262144*4    =  1,048,576
constexpr size_t WS_NEED  = S1_OFF + 1048576;           // ~118 MB

__device__ __forceinline__ short f2bf(float f) {
  union { float f; unsigned u; } v; v.f = f;
  unsigned r = v.u + 0x7FFFu + ((v.u >> 16) & 1u);   // round-to-nearest-even
  return (short)(r >> 16);
}

__device__ __forceinline__ float bf2f(short s) {
  union { unsigned u; float f; } v; v.u = ((unsigned)(unsigned short)s) << 16;
  return v.f;
}

__device__ __forceinline__ bf16x8 pack8(f32x4 a, f32x4 b) {
  bf16x8 f;
  f[0] = f2bf(a[0]); f[1] = f2bf(a[1]); f[2] = f2bf(a[2]); f[3] = f2bf(a[3]);
  f[4] = f2bf(b[0]); f[5] = f2bf(b[1]); f[6] = f2bf(b[2]); f[7] = f2bf(b[3]);
  return f;
}

// LDS row offset for transposed u-tile ulds[r][c] (shorts): rows 16B-aligned
// (b128 legal for proj), 8-row stride = 4 mod 32 banks (conflict-lite).
__device__ __forceinline__ int rowoff(int r) { return r * 264 + ((r >> 3) << 3); }

// ---------------- P0: pack x + yws=diag*x + proj level 0 ----------------
__global__ __launch_bounds__(256, 4) void k_p0(
    const float* __restrict__ x, const float* __restrict__ diag,
    const float* __restrict__ u, unsigned short* __restrict__ xb,
    float* __restrict__ yws, short* __restrict__ part)
{
  __shared__ alignas(16) short ulds[64 * 264 + 64];   // 33,920 B -> 4 wg/CU

  const int c0   = blockIdx.x * CHUNK;
  const int tid  = threadIdx.x;
  const int w    = tid >> 6;
  const int lane = tid & 63;
  const int lg   = lane >> 4;
  const int lr   = lane & 15;
  const int bw   = 16 * w;

  // stage u_0 row (c0+tid) transposed into LDS (HBM loads issued first)
  {
    const float* ug = u + (size_t)(c0 + tid) * RANK;
    #pragma unroll
    for (int h = 0; h < 4; ++h) {
      f32x4 t[4];
      #pragma unroll
      for (int q = 0; q < 4; ++q) t[q] = *(const f32x4*)(ug + h * 16 + q * 4);
      #pragma unroll
      for (int q = 0; q < 4; ++q) {
        #pragma unroll
        for (int e = 0; e < 4; ++e) {
          const int r = h * 16 + q * 4 + e;
          ulds[rowoff(r) + tid] = f2bf(t[q][e]);
        }
      }
    }
  }

  // pack x -> xf (regs) + xb (bf16), and yws = diag*x (fp32 exact)
  bf16x8 xf[8];
  {
    const size_t rowbase = (size_t)(bw + lr) * NN + c0 + lg * 8;
    const float* xp = x + rowbase;
    float* yp = yws + rowbase;
    unsigned short* xbp = xb + rowbase;
    #pragma unroll
    for (int s = 0; s < 8; ++s) {
      f32x4 a = *(const f32x4*)(xp + s * 32);
      f32x4 b = *(const f32x4*)(xp + s * 32 + 4);
      xf[s] = pack8(a, b);
      *(bf16x8*)(xbp + s * 32) = xf[s];
      f32x4 da = *(const f32x4*)(diag + c0 + s * 32 + lg * 8);
      f32x4 db = *(const f32x4*)(diag + c0 + s * 32 + lg * 8 + 4);
      f32x4 ya, yb;
      #pragma unroll
      for (int j = 0; j < 4; ++j) { ya[j] = a[j] * da[j]; yb[j] = b[j] * db[j]; }
      *(f32x4*)(yp + s * 32) = ya;
      *(f32x4*)(yp + s * 32 + 4) = yb;
    }
  }
  __syncthreads();

  // proj level 0
  {
    short* pb = part + (size_t)blockIdx.x * (BATCH * RANK);
    #pragma unroll
    for (int rt = 0; rt < 4; ++rt) {
      f32x4 pacc = (f32x4){0.f, 0.f, 0.f, 0.f};
      const int rbase = rowoff(rt * 16 + lr);
      #pragma unroll
      for (int s = 0; s < 8; ++s) {
        bf16x8 bf = *(const bf16x8*)&ulds[rbase + s * 32 + lg * 8];
        pacc = __builtin_amdgcn_mfma_f32_16x16x32_bf16(xf[s], bf, pacc, 0, 0, 0);
      }
      #pragma unroll
      for (int v = 0; v < 4; ++v)              // D: row = lg*4+v, col = lr
        pb[(bw + lg * 4 + v) * RANK + rt * 16 + lr] = f2bf(pacc[v]);
    }
  }
}

// ---------------- RED kernels: part -> ts (plain stores) ----------------
// L<=2 stage 1: grid 1024; thread T sums 16 chunk-partials -> s1[T]
__global__ __launch_bounds__(256, 4) void k_red1(
    const short* __restrict__ part, float* __restrict__ s1, const int L)
{
  const int T = blockIdx.x * NTHR + threadIdx.x;
  const int entries = 1 << (13 + L);
  const int contrib = 512 >> L;
  const int e   = T & (entries - 1);
  const int grp = T >> (13 + L);
  const int blk = e >> 12, br = e & 4095;
  const short* p = part + (size_t)(blk * contrib + grp * 16) * 4096 + br;
  float s = 0.f;
  #pragma unroll
  for (int k = 0; k < 16; ++k) s += bf2f(p[(size_t)k * 4096]);
  s1[T] = s;
}

// L<=2 stage 2: grid entries/256; thread e sums G group-partials -> ts
__global__ __launch_bounds__(256, 4) void k_red2(
    const float* __restrict__ s1, float* __restrict__ ts, const int L)
{
  const int e = blockIdx.x * NTHR + threadIdx.x;
  const int entries = 1 << (13 + L);
  const int G = 32 >> L;
  const size_t tsbase = (size_t)((1 << (L + 1)) - 2) * (BATCH * RANK);
  float s = 0.f;
  for (int g = 0; g < G; ++g) s += s1[(size_t)g * entries + e];
  ts[tsbase + e] = s;
}

// L>=3 single stage: grid entries/256; thread e sums contrib partials
__global__ __launch_bounds__(256, 4) void k_redB(
    const short* __restrict__ part, float* __restrict__ ts, const int L)
{
  const int e = blockIdx.x * NTHR + threadIdx.x;
  const int contrib = 512 >> L;              // 64,32,16,8,4
  const size_t tsbase = (size_t)((1 << (L + 1)) - 2) * (BATCH * RANK);
  const int blk = e >> 12, br = e & 4095;
  const short* p = part + (size_t)(blk * contrib) * 4096 + br;
  float s = 0.f;
  for (int k = 0; k < contrib; ++k) s += bf2f(p[(size_t)k * 4096]);
  ts[tsbase + e] = s;
}

// ---------------- PE_L: stage u_{L+1}; exp_L (u from LLC); proj_{L+1} ----
__global__ __launch_bounds__(256, 4) void k_pe(
    const unsigned short* __restrict__ xb, const float* __restrict__ u,
    short* __restrict__ part, const float* __restrict__ ts,
    float* __restrict__ yws, const int L)
{
  __shared__ alignas(16) short ulds[64 * 264 + 64];

  const int c0   = blockIdx.x * CHUNK;
  const int tid  = threadIdx.x;
  const int w    = tid >> 6;
  const int lane = tid & 63;
  const int lg   = lane >> 4;
  const int lr   = lane & 15;
  const int bw   = 16 * w;

  // (1) stage u_{L+1} transposed into LDS -- the kernel's only HBM stream,
  // issued first so it overlaps the LLC-bound exp phase below.
  {
    const float* ug = u + ((size_t)(L + 1) * NN + c0 + tid) * RANK;
    #pragma unroll
    for (int h = 0; h < 4; ++h) {
      f32x4 t[4];
      #pragma unroll
      for (int q = 0; q < 4; ++q) t[q] = *(const f32x4*)(ug + h * 16 + q * 4);
      #pragma unroll
      for (int q = 0; q < 4; ++q) {
        #pragma unroll
        for (int e = 0; e < 4; ++e) {
          const int r = h * 16 + q * 4 + e;
          ulds[rowoff(r) + tid] = f2bf(t[q][e]);
        }
      }
    }
  }

  // (2) exp level L: u_L re-read from global (LLC-resident), yws += U t_sib
  {
    const int blk = c0 >> (17 - L);
    const int off = (1 << (L + 1)) - 2;
    const float* tb = ts + (size_t)(off + (blk ^ 1)) * (BATCH * RANK);

    bf16x8 af[2];
    #pragma unroll
    for (int s2 = 0; s2 < 2; ++s2) {
      const float* p = tb + (size_t)(bw + lr) * RANK + s2 * 32 + lg * 8;
      af[s2] = pack8(*(const f32x4*)p, *(const f32x4*)(p + 4));
    }

    f32x4 yacc[16];
    #pragma unroll
    for (int ct = 0; ct < 16; ++ct) yacc[ct] = (f32x4){0.f, 0.f, 0.f, 0.f};

    const float* ub = u + ((size_t)L * NN + c0) * RANK;
    #pragma unroll
    for (int ct = 0; ct < 16; ++ct) {
      const float* up = ub + (size_t)(ct * 16 + lr) * RANK + lg * 8;
      #pragma unroll
      for (int s2 = 0; s2 < 2; ++s2) {
        f32x4 a = *(const f32x4*)(up + s2 * 32);
        f32x4 b = *(const f32x4*)(up + s2 * 32 + 4);
        yacc[ct] = __builtin_amdgcn_mfma_f32_16x16x32_bf16(af[s2], pack8(a, b),
                                                           yacc[ct], 0, 0, 0);
      }
    }

    #pragma unroll
    for (int ct = 0; ct < 16; ++ct) {
      const int c = c0 + ct * 16 + lr;
      #pragma unroll
      for (int v = 0; v < 4; ++v) {
        const size_t idx = (size_t)(bw + lg * 4 + v) * NN + c;
        yws[idx] += yacc[ct][v];
      }
    }
  }

  // (3) proj level L+1 from the staged LDS tile
  bf16x8 xf[8];
  {
    const unsigned short* xp = xb + (size_t)(bw + lr) * NN + c0 + lg * 8;
    #pragma unroll
    for (int s = 0; s < 8; ++s) xf[s] = *(const bf16x8*)(xp + s * 32);
  }
  __syncthreads();
  {
    short* pb = part + (size_t)blockIdx.x * (BATCH * RANK);
    #pragma unroll
    for (int rt = 0; rt < 4; ++rt) {
      f32x4 pacc = (f32x4){0.f, 0.f, 0.f, 0.f};
      const int rbase = rowoff(rt * 16 + lr);
      #pragma unroll
      for (int s = 0; s < 8; ++s) {
        bf16x8 bf = *(const bf16x8*)&ulds[rbase + s * 32 + lg * 8];
        pacc = __builtin_amdgcn_mfma_f32_16x16x32_bf16(xf[s], bf, pacc, 0, 0, 0);
      }
      #pragma unroll
      for (int v = 0; v < 4; ++v)
        pb[(bw + lg * 4 + v) * RANK + rt * 16 + lr] = f2bf(pacc[v]);
    }
  }
}

// ---------------- EF: exp level 7 + final y = yws + acc ----------------
__global__ __launch_bounds__(256, 4) void k_ef(
    const float* __restrict__ u, const float* __restrict__ ts,
    const float* __restrict__ yws, float* __restrict__ y)
{
  const int c0   = blockIdx.x * CHUNK;
  const int tid  = threadIdx.x;
  const int w    = tid >> 6;
  const int lane = tid & 63;
  const int lg   = lane >> 4;
  const int lr   = lane & 15;
  const int bw   = 16 * w;

  const int blk = c0 >> 10;                  // L=7: block size 1024
  const float* tb = ts + (size_t)(254 + (blk ^ 1)) * (BATCH * RANK);

  bf16x8 af[2];
  #pragma unroll
  for (int s2 = 0; s2 < 2; ++s2) {
    const float* p = tb + (size_t)(bw + lr) * RANK + s2 * 32 + lg * 8;
    af[s2] = pack8(*(const f32x4*)p, *(const f32x4*)(p + 4));
  }

  f32x4 yacc[16];
  #pragma unroll
  for (int ct = 0; ct < 16; ++ct) yacc[ct] = (f32x4){0.f, 0.f, 0.f, 0.f};

  const float* ub = u + ((size_t)7 * NN + c0) * RANK;
  #pragma unroll
  for (int ct = 0; ct < 16; ++ct) {
    const float* up = ub + (size_t)(ct * 16 + lr) * RANK + lg * 8;
    #pragma unroll
    for (int s2 = 0; s2 < 2; ++s2) {
      f32x4 a = *(const f32x4*)(up + s2 * 32);
      f32x4 b = *(const f32x4*)(up + s2 * 32 + 4);
      yacc[ct] = __builtin_amdgcn_mfma_f32_16x16x32_bf16(af[s2], pack8(a, b),
                                                         yacc[ct], 0, 0, 0);
    }
  }

  #pragma unroll
  for (int ct = 0; ct < 16; ++ct) {
    const int c = c0 + ct * 16 + lr;
    #pragma unroll
    for (int v = 0; v < 4; ++v) {
      const size_t idx = (size_t)(bw + lg * 4 + v) * NN + c;
      y[idx] = yws[idx] + yacc[ct][v];
    }
  }
}

// ================= legacy 3-kernel path (fallback only, proven 464 us) ======

__global__ __launch_bounds__(256, 4) void k_proj2(
    const float* __restrict__ x, const float* __restrict__ u,
    short* __restrict__ part)
{
  __shared__ alignas(16) short ulds[RANK * LSTR];

  const int c0   = blockIdx.x * CHUNK;
  const int tid  = threadIdx.x;
  const int w    = tid >> 6;
  const int lane = tid & 63;
  const int lg   = lane >> 4;
  const int lr   = lane & 15;

  bf16x8 xf[CHUNK / 32];
  {
    const float* xp = x + (size_t)(16 * w + lr) * NN + c0 + lg * 8;
    #pragma unroll
    for (int s = 0; s < CHUNK / 32; ++s) {
      f32x4 a = *(const f32x4*)(xp + s * 32);
      f32x4 b = *(const f32x4*)(xp + s * 32 + 4);
      xf[s] = pack8(a, b);
    }
  }

  for (int i = 0; i < DEPTH; ++i) {
    __syncthreads();
    {
      const float* ug = u + ((size_t)i * NN + c0 + tid) * RANK;
      short* col = &ulds[tid];
      #pragma unroll
      for (int h = 0; h < 2; ++h) {
        f32x4 t[8];
        #pragma unroll
        for (int q = 0; q < 8; ++q) t[q] = *(const f32x4*)(ug + h * 32 + q * 4);
        #pragma unroll
        for (int q = 0; q < 8; ++q) {
          #pragma unroll
          for (int e = 0; e < 4; ++e)
            col[(h * 32 + q * 4 + e) * LSTR] = f2bf(t[q][e]);
        }
      }
    }
    __syncthreads();

    f32x4 pacc[4];
    #pragma unroll
    for (int rt = 0; rt < 4; ++rt) pacc[rt] = (f32x4){0.f, 0.f, 0.f, 0.f};
    #pragma unroll
    for (int s = 0; s < CHUNK / 32; ++s) {
      #pragma unroll
      for (int rt = 0; rt < 4; ++rt) {
        bf16x8 bf = *(const bf16x8*)&ulds[(rt * 16 + lr) * LSTR + s * 32 + lg * 8];
        pacc[rt] = __builtin_amdgcn_mfma_f32_16x16x32_bf16(xf[s], bf, pacc[rt], 0, 0, 0);
      }
    }

    short* pb = part + ((size_t)i * NCHUNK + blockIdx.x) * (BATCH * RANK);
    #pragma unroll
    for (int rt = 0; rt < 4; ++rt) {
      #pragma unroll
      for (int v = 0; v < 4; ++v) {
        const int b = 16 * w + lg * 4 + v;
        pb[b * RANK + rt * 16 + lr] = f2bf(pacc[rt][v]);
      }
    }
  }
}

__global__ __launch_bounds__(256, 4) void k_reduce(
    const short* __restrict__ part, float* __restrict__ ts)
{
  int g = blockIdx.x;
  int lvl = 0;
  while (g >= ((2 << lvl) * 16)) { g -= (2 << lvl) * 16; ++lvl; }
  const int block = g >> 4;
  const int bq = (g >> 2) & 3;
  const int rq = g & 3;
  const int contrib = 512 >> lvl;
  const int chunk0  = block * contrib;

  const int b = bq * 16 + (threadIdx.x >> 4);
  const int r = rq * 16 + (threadIdx.x & 15);

  const short* p = part + ((size_t)lvl * NCHUNK + chunk0) * (BATCH * RANK) + b * RANK + r;
  float s = 0.f;
  int k = 0;
  for (; k + 8 <= contrib; k += 8) {
    float a0 = bf2f(p[(size_t)(k + 0) * 4096]);
    float a1 = bf2f(p[(size_t)(k + 1) * 4096]);
    float a2 = bf2f(p[(size_t)(k + 2) * 4096]);
    float a3 = bf2f(p[(size_t)(k + 3) * 4096]);
    float a4 = bf2f(p[(size_t)(k + 4) * 4096]);
    float a5 = bf2f(p[(size_t)(k + 5) * 4096]);
    float a6 = bf2f(p[(size_t)(k + 6) * 4096]);
    float a7 = bf2f(p[(size_t)(k + 7) * 4096]);
    s += ((a0 + a1) + (a2 + a3)) + ((a4 + a5) + (a6 + a7));
  }
  for (; k < contrib; ++k) s += bf2f(p[(size_t)k * 4096]);

  const int off = (1 << (lvl + 1)) - 2;
  ts[(size_t)(off + block) * (BATCH * RANK) + b * RANK + r] = s;
}

__global__ __launch_bounds__(256, 4) void k_exp2(
    const float* __restrict__ x, const float* __restrict__ diag,
    const float* __restrict__ u, const float* __restrict__ ts,
    float* __restrict__ y)
{
  const int cw0  = blockIdx.x * WIN;
  const int tid  = threadIdx.x;
  const int w    = tid >> 6;
  const int lane = tid & 63;
  const int lg   = lane >> 4;
  const int lr   = lane & 15;
  const int bw   = 16 * w;

  f32x4 yacc[16];
  #pragma unroll
  for (int ct = 0; ct < 16; ++ct) yacc[ct] = (f32x4){0.f, 0.f, 0.f, 0.f};

  #pragma unroll
  for (int i = 0; i < DEPTH; ++i) {
    const int blk = cw0 >> (17 - i);
    const int off = (1 << (i + 1)) - 2;
    const float* tb = ts + (size_t)(off + (blk ^ 1)) * (BATCH * RANK);

    bf16x8 af[2];
    #pragma unroll
    for (int s2 = 0; s2 < 2; ++s2) {
      const float* p = tb + (size_t)(bw + lr) * RANK + s2 * 32 + lg * 8;
      af[s2] = pack8(*(const f32x4*)p, *(const f32x4*)(p + 4));
    }

    const float* ub = u + ((size_t)i * NN + cw0) * RANK;
    #pragma unroll
    for (int ct = 0; ct < 16; ++ct) {
      const float* up = ub + (size_t)(ct * 16 + lr) * RANK + lg * 8;
      #pragma unroll
      for (int s2 = 0; s2 < 2; ++s2) {
        f32x4 a = *(const f32x4*)(up + s2 * 32);
        f32x4 b = *(const f32x4*)(up + s2 * 32 + 4);
        yacc[ct] = __builtin_amdgcn_mfma_f32_16x16x32_bf16(af[s2], pack8(a, b), yacc[ct], 0, 0, 0);
      }
    }
  }

  #pragma unroll
  for (int ct = 0; ct < 16; ++ct) {
    const int c = cw0 + ct * 16 + lr;
    const float dg = diag[c];
    #pragma unroll
    for (int v = 0; v < 4; ++v) {
      const int b = bw + lg * 4 + v;
      const size_t idx = (size_t)b * NN + c;
      y[idx] = yacc[ct][v] + dg * x[idx];
    }
  }
}

extern "C" void kernel_launch(void* const* d_in, const int* in_sizes, int n_in,
                              void* d_out, int out_size, void* d_ws, size_t ws_size,
                              hipStream_t stream) {
  (void)in_sizes; (void)n_in; (void)out_size;
  const float* x    = (const float*)d_in[0];
  const float* diag = (const float*)d_in[1];
  const float* u    = (const float*)d_in[2];
  float* y = (float*)d_out;
  char* wsb = (char*)d_ws;

  if (ws_size >= WS_NEED) {
    float*          yws  = (float*)(wsb + YWS_OFF);
    unsigned short* xb   = (unsigned short*)(wsb + XB_OFF);
    short*          part = (short*)(wsb + PART_OFF);
    float*          ts   = (float*)(wsb + TS_OFF);
    float*          s1   = (float*)(wsb + S1_OFF);

    k_p0<<<NCHUNK, NTHR, 0, stream>>>(x, diag, u, xb, yws, part);
    for (int L = 0; L < DEPTH; ++L) {
      const int entries = 1 << (13 + L);
      if (L <= 2) {
        k_red1<<<NCHUNK, NTHR, 0, stream>>>(part, s1, L);
        k_red2<<<entries / NTHR, NTHR, 0, stream>>>(s1, ts, L);
      } else {
        k_redB<<<entries / NTHR, NTHR, 0, stream>>>(part, ts, L);
      }
      if (L < DEPTH - 1)
        k_pe<<<NCHUNK, NTHR, 0, stream>>>(xb, u, part, ts, yws, L);
      else
        k_ef<<<NCHUNK, NTHR, 0, stream>>>(u, ts, yws, y);
    }
  } else {
    // fallback: proven three-launch path (464 us baseline)
    short* part = (short*)d_out;
    float* ts   = (float*)d_ws;
    k_proj2 <<<NCHUNK, 256, 0, stream>>>(x, u, part);
    k_reduce<<<8160,   256, 0, stream>>>(part, ts);
    k_exp2  <<<NN / WIN, 256, 0, stream>>>(x, diag, u, ts, y);
  }
}

// Round 7
// 696.476 us; speedup vs baseline: 2.5636x; 1.0132x over previous
//
#include <hip/hip_runtime.h>

// HODLR matvec, round 7: proven 3-launch structure, occupancy-focused.
// All prior read-heavy kernels plateaued at ~2-3 TB/s with occupancy pinned
// at 4 wgs/CU (grid=1024 exactly covers 256 CUs; 34KB LDS; 128 V+A regs).
// This round halves per-wg footprint to double resident waves:
//   k_proj3: CHUNK=128, grid 2048, LDS 17KB, single pacc quad
//   k_red3 : contrib = 1024>>lvl (part has 2048 chunks), grid 8160
//   k_exp3 : WIN=128, grid 2048, yacc[8]
// part (134 MB) lives in ws; ts unchanged. Legacy trio kept as fallback.

typedef __attribute__((ext_vector_type(8))) short bf16x8;
typedef __attribute__((ext_vector_type(4))) float f32x4;

constexpr int BATCH = 64;
constexpr int NN    = 262144;   // 2^18 nodes
constexpr int RANK  = 64;
constexpr int DEPTH = 8;

// new-path geometry
constexpr int CH2   = 128;              // proj chunk (cols per wg)
constexpr int NCH2  = NN / CH2;         // 2048
constexpr int LSTR2 = 136;              // shorts per rank-row (bank step 4, 16B-aligned)
constexpr int WIN2  = 128;              // exp window
// ws layout (bytes)
constexpr size_t PART2_BYTES = (size_t)DEPTH * NCH2 * BATCH * RANK * 2;  // 134,217,728
constexpr size_t TS2_OFF     = PART2_BYTES;
constexpr size_t WS_NEED2    = TS2_OFF + 510ull * 4096 * 4;              // ~142.6 MB

// legacy geometry (fallback)
constexpr int CHUNK = 256;
constexpr int NCHUNK = NN / CHUNK;      // 1024
constexpr int LSTR  = 264;
constexpr int WIN   = 256;

__device__ __forceinline__ short f2bf(float f) {
  union { float f; unsigned u; } v; v.f = f;
  unsigned r = v.u + 0x7FFFu + ((v.u >> 16) & 1u);   // round-to-nearest-even
  return (short)(r >> 16);
}

__device__ __forceinline__ float bf2f(short s) {
  union { unsigned u; float f; } v; v.u = ((unsigned)(unsigned short)s) << 16;
  return v.f;
}

__device__ __forceinline__ bf16x8 pack8(f32x4 a, f32x4 b) {
  bf16x8 f;
  f[0] = f2bf(a[0]); f[1] = f2bf(a[1]); f[2] = f2bf(a[2]); f[3] = f2bf(a[3]);
  f[4] = f2bf(b[0]); f[5] = f2bf(b[1]); f[6] = f2bf(b[2]); f[7] = f2bf(b[3]);
  return f;
}

// ---------------- k_proj3: projection, CHUNK=128, high occupancy ----------
// grid 2048 x 256 thr. LDS 64x136 shorts = 17,408 B. Single pacc quad.
__global__ __launch_bounds__(256, 6) void k_proj3(
    const float* __restrict__ x, const float* __restrict__ u,
    short* __restrict__ part)
{
  __shared__ alignas(16) short ulds[RANK * LSTR2];   // 17,408 B

  const int c0   = blockIdx.x * CH2;
  const int tid  = threadIdx.x;
  const int w    = tid >> 6;
  const int lane = tid & 63;
  const int lg   = lane >> 4;
  const int lr   = lane & 15;
  const int col  = tid & 127;      // 2 threads per column
  const int half = tid >> 7;       // each stages 32 ranks

  // x A-fragments: lane holds x[16w+lr][c0 + s*32 + lg*8 + j]
  bf16x8 xf[CH2 / 32];
  {
    const float* xp = x + (size_t)(16 * w + lr) * NN + c0 + lg * 8;
    #pragma unroll
    for (int s = 0; s < CH2 / 32; ++s) {
      f32x4 a = *(const f32x4*)(xp + s * 32);
      f32x4 b = *(const f32x4*)(xp + s * 32 + 4);
      xf[s] = pack8(a, b);
    }
  }

  for (int i = 0; i < DEPTH; ++i) {
    __syncthreads();   // previous level's MFMA reads done
    // stage u rows (c0+col), ranks half*32..+31, transposed: ulds[r][col]
    {
      const float* ug = u + ((size_t)i * NN + c0 + col) * RANK + half * 32;
      #pragma unroll
      for (int h = 0; h < 2; ++h) {
        f32x4 t[4];
        #pragma unroll
        for (int q = 0; q < 4; ++q) t[q] = *(const f32x4*)(ug + h * 16 + q * 4);
        #pragma unroll
        for (int q = 0; q < 4; ++q) {
          #pragma unroll
          for (int e = 0; e < 4; ++e)
            ulds[(half * 32 + h * 16 + q * 4 + e) * LSTR2 + col] = f2bf(t[q][e]);
        }
      }
    }
    __syncthreads();

    // MFMA: one rt quad at a time (4 AGPR live)
    short* pb = part + ((size_t)i * NCH2 + blockIdx.x) * (BATCH * RANK);
    #pragma unroll
    for (int rt = 0; rt < 4; ++rt) {
      f32x4 pacc = (f32x4){0.f, 0.f, 0.f, 0.f};
      const int rbase = (rt * 16 + lr) * LSTR2;
      #pragma unroll
      for (int s = 0; s < CH2 / 32; ++s) {
        bf16x8 bf = *(const bf16x8*)&ulds[rbase + s * 32 + lg * 8];
        pacc = __builtin_amdgcn_mfma_f32_16x16x32_bf16(xf[s], bf, pacc, 0, 0, 0);
      }
      #pragma unroll
      for (int v = 0; v < 4; ++v)              // D: row = lg*4+v, col = lr
        pb[(16 * w + lg * 4 + v) * RANK + rt * 16 + lr] = f2bf(pacc[v]);
    }
  }
}

// ---------------- k_red3: partial reduction -> ts fp32 --------------------
// grid = sum_i 2^(i+1)*16 = 8160; wg = one (level, block, 16b x 16r subtile).
__global__ __launch_bounds__(256, 4) void k_red3(
    const short* __restrict__ part, float* __restrict__ ts)
{
  int g = blockIdx.x;
  int lvl = 0;
  while (g >= ((2 << lvl) * 16)) { g -= (2 << lvl) * 16; ++lvl; }
  const int block = g >> 4;
  const int bq = (g >> 2) & 3;
  const int rq = g & 3;
  const int contrib = 1024 >> lvl;          // chunks per block (CH2=128)
  const int chunk0  = block * contrib;

  const int b = bq * 16 + (threadIdx.x >> 4);
  const int r = rq * 16 + (threadIdx.x & 15);

  const short* p = part + ((size_t)lvl * NCH2 + chunk0) * (BATCH * RANK) + b * RANK + r;
  float s = 0.f;
  int k = 0;
  for (; k + 8 <= contrib; k += 8) {
    float a0 = bf2f(p[(size_t)(k + 0) * 4096]);
    float a1 = bf2f(p[(size_t)(k + 1) * 4096]);
    float a2 = bf2f(p[(size_t)(k + 2) * 4096]);
    float a3 = bf2f(p[(size_t)(k + 3) * 4096]);
    float a4 = bf2f(p[(size_t)(k + 4) * 4096]);
    float a5 = bf2f(p[(size_t)(k + 5) * 4096]);
    float a6 = bf2f(p[(size_t)(k + 6) * 4096]);
    float a7 = bf2f(p[(size_t)(k + 7) * 4096]);
    s += ((a0 + a1) + (a2 + a3)) + ((a4 + a5) + (a6 + a7));
  }
  for (; k < contrib; ++k) s += bf2f(p[(size_t)k * 4096]);

  const int off = (1 << (lvl + 1)) - 2;
  ts[(size_t)(off + block) * (BATCH * RANK) + b * RANK + r] = s;
}

// ---------------- k_exp3: expansion, WIN=128, high occupancy --------------
// grid 2048 x 256 thr, no LDS, yacc[8] = 32 AGPR.
__global__ __launch_bounds__(256, 6) void k_exp3(
    const float* __restrict__ x, const float* __restrict__ diag,
    const float* __restrict__ u, const float* __restrict__ ts,
    float* __restrict__ y)
{
  const int cw0  = blockIdx.x * WIN2;
  const int tid  = threadIdx.x;
  const int w    = tid >> 6;
  const int lane = tid & 63;
  const int lg   = lane >> 4;
  const int lr   = lane & 15;
  const int bw   = 16 * w;

  f32x4 yacc[WIN2 / 16];
  #pragma unroll
  for (int ct = 0; ct < WIN2 / 16; ++ct) yacc[ct] = (f32x4){0.f, 0.f, 0.f, 0.f};

  #pragma unroll
  for (int i = 0; i < DEPTH; ++i) {
    const int blk = cw0 >> (17 - i);
    const int off = (1 << (i + 1)) - 2;
    const float* tb = ts + (size_t)(off + (blk ^ 1)) * (BATCH * RANK);

    // A fragments (t_sib): lane holds t[bw+lr][s2*32 + lg*8 + j]
    bf16x8 af[2];
    #pragma unroll
    for (int s2 = 0; s2 < 2; ++s2) {
      const float* p = tb + (size_t)(bw + lr) * RANK + s2 * 32 + lg * 8;
      af[s2] = pack8(*(const f32x4*)p, *(const f32x4*)(p + 4));
    }

    const float* ub = u + ((size_t)i * NN + cw0) * RANK;
    #pragma unroll
    for (int ct = 0; ct < WIN2 / 16; ++ct) {
      const float* up = ub + (size_t)(ct * 16 + lr) * RANK + lg * 8;
      #pragma unroll
      for (int s2 = 0; s2 < 2; ++s2) {
        f32x4 a = *(const f32x4*)(up + s2 * 32);
        f32x4 b = *(const f32x4*)(up + s2 * 32 + 4);
        yacc[ct] = __builtin_amdgcn_mfma_f32_16x16x32_bf16(af[s2], pack8(a, b),
                                                           yacc[ct], 0, 0, 0);
      }
    }
  }

  // epilogue: y = yacc + diag*x. D: col=lr (c), row=lg*4+v (b)
  #pragma unroll
  for (int ct = 0; ct < WIN2 / 16; ++ct) {
    const int c = cw0 + ct * 16 + lr;
    const float dg = diag[c];
    #pragma unroll
    for (int v = 0; v < 4; ++v) {
      const int b = bw + lg * 4 + v;
      const size_t idx = (size_t)b * NN + c;
      y[idx] = yacc[ct][v] + dg * x[idx];
    }
  }
}

// ================= legacy 3-kernel path (fallback only, proven 464 us) ======

__global__ __launch_bounds__(256, 4) void k_proj2(
    const float* __restrict__ x, const float* __restrict__ u,
    short* __restrict__ part)
{
  __shared__ alignas(16) short ulds[RANK * LSTR];

  const int c0   = blockIdx.x * CHUNK;
  const int tid  = threadIdx.x;
  const int w    = tid >> 6;
  const int lane = tid & 63;
  const int lg   = lane >> 4;
  const int lr   = lane & 15;

  bf16x8 xf[CHUNK / 32];
  {
    const float* xp = x + (size_t)(16 * w + lr) * NN + c0 + lg * 8;
    #pragma unroll
    for (int s = 0; s < CHUNK / 32; ++s) {
      f32x4 a = *(const f32x4*)(xp + s * 32);
      f32x4 b = *(const f32x4*)(xp + s * 32 + 4);
      xf[s] = pack8(a, b);
    }
  }

  for (int i = 0; i < DEPTH; ++i) {
    __syncthreads();
    {
      const float* ug = u + ((size_t)i * NN + c0 + tid) * RANK;
      short* col = &ulds[tid];
      #pragma unroll
      for (int h = 0; h < 2; ++h) {
        f32x4 t[8];
        #pragma unroll
        for (int q = 0; q < 8; ++q) t[q] = *(const f32x4*)(ug + h * 32 + q * 4);
        #pragma unroll
        for (int q = 0; q < 8; ++q) {
          #pragma unroll
          for (int e = 0; e < 4; ++e)
            col[(h * 32 + q * 4 + e) * LSTR] = f2bf(t[q][e]);
        }
      }
    }
    __syncthreads();

    f32x4 pacc[4];
    #pragma unroll
    for (int rt = 0; rt < 4; ++rt) pacc[rt] = (f32x4){0.f, 0.f, 0.f, 0.f};
    #pragma unroll
    for (int s = 0; s < CHUNK / 32; ++s) {
      #pragma unroll
      for (int rt = 0; rt < 4; ++rt) {
        bf16x8 bf = *(const bf16x8*)&ulds[(rt * 16 + lr) * LSTR + s * 32 + lg * 8];
        pacc[rt] = __builtin_amdgcn_mfma_f32_16x16x32_bf16(xf[s], bf, pacc[rt], 0, 0, 0);
      }
    }

    short* pb = part + ((size_t)i * NCHUNK + blockIdx.x) * (BATCH * RANK);
    #pragma unroll
    for (int rt = 0; rt < 4; ++rt) {
      #pragma unroll
      for (int v = 0; v < 4; ++v) {
        const int b = 16 * w + lg * 4 + v;
        pb[b * RANK + rt * 16 + lr] = f2bf(pacc[rt][v]);
      }
    }
  }
}

__global__ __launch_bounds__(256, 4) void k_reduce(
    const short* __restrict__ part, float* __restrict__ ts)
{
  int g = blockIdx.x;
  int lvl = 0;
  while (g >= ((2 << lvl) * 16)) { g -= (2 << lvl) * 16; ++lvl; }
  const int block = g >> 4;
  const int bq = (g >> 2) & 3;
  const int rq = g & 3;
  const int contrib = 512 >> lvl;
  const int chunk0  = block * contrib;

  const int b = bq * 16 + (threadIdx.x >> 4);
  const int r = rq * 16 + (threadIdx.x & 15);

  const short* p = part + ((size_t)lvl * NCHUNK + chunk0) * (BATCH * RANK) + b * RANK + r;
  float s = 0.f;
  int k = 0;
  for (; k + 8 <= contrib; k += 8) {
    float a0 = bf2f(p[(size_t)(k + 0) * 4096]);
    float a1 = bf2f(p[(size_t)(k + 1) * 4096]);
    float a2 = bf2f(p[(size_t)(k + 2) * 4096]);
    float a3 = bf2f(p[(size_t)(k + 3) * 4096]);
    float a4 = bf2f(p[(size_t)(k + 4) * 4096]);
    float a5 = bf2f(p[(size_t)(k + 5) * 4096]);
    float a6 = bf2f(p[(size_t)(k + 6) * 4096]);
    float a7 = bf2f(p[(size_t)(k + 7) * 4096]);
    s += ((a0 + a1) + (a2 + a3)) + ((a4 + a5) + (a6 + a7));
  }
  for (; k < contrib; ++k) s += bf2f(p[(size_t)k * 4096]);

  const int off = (1 << (lvl + 1)) - 2;
  ts[(size_t)(off + block) * (BATCH * RANK) + b * RANK + r] = s;
}

__global__ __launch_bounds__(256, 4) void k_exp2(
    const float* __restrict__ x, const float* __restrict__ diag,
    const float* __restrict__ u, const float* __restrict__ ts,
    float* __restrict__ y)
{
  const int cw0  = blockIdx.x * WIN;
  const int tid  = threadIdx.x;
  const int w    = tid >> 6;
  const int lane = tid & 63;
  const int lg   = lane >> 4;
  const int lr   = lane & 15;
  const int bw   = 16 * w;

  f32x4 yacc[16];
  #pragma unroll
  for (int ct = 0; ct < 16; ++ct) yacc[ct] = (f32x4){0.f, 0.f, 0.f, 0.f};

  #pragma unroll
  for (int i = 0; i < DEPTH; ++i) {
    const int blk = cw0 >> (17 - i);
    const int off = (1 << (i + 1)) - 2;
    const float* tb = ts + (size_t)(off + (blk ^ 1)) * (BATCH * RANK);

    bf16x8 af[2];
    #pragma unroll
    for (int s2 = 0; s2 < 2; ++s2) {
      const float* p = tb + (size_t)(bw + lr) * RANK + s2 * 32 + lg * 8;
      af[s2] = pack8(*(const f32x4*)p, *(const f32x4*)(p + 4));
    }

    const float* ub = u + ((size_t)i * NN + cw0) * RANK;
    #pragma unroll
    for (int ct = 0; ct < 16; ++ct) {
      const float* up = ub + (size_t)(ct * 16 + lr) * RANK + lg * 8;
      #pragma unroll
      for (int s2 = 0; s2 < 2; ++s2) {
        f32x4 a = *(const f32x4*)(up + s2 * 32);
        f32x4 b = *(const f32x4*)(up + s2 * 32 + 4);
        yacc[ct] = __builtin_amdgcn_mfma_f32_16x16x32_bf16(af[s2], pack8(a, b), yacc[ct], 0, 0, 0);
      }
    }
  }

  #pragma unroll
  for (int ct = 0; ct < 16; ++ct) {
    const int c = cw0 + ct * 16 + lr;
    const float dg = diag[c];
    #pragma unroll
    for (int v = 0; v < 4; ++v) {
      const int b = bw + lg * 4 + v;
      const size_t idx = (size_t)b * NN + c;
      y[idx] = yacc[ct][v] + dg * x[idx];
    }
  }
}

extern "C" void kernel_launch(void* const* d_in, const int* in_sizes, int n_in,
                              void* d_out, int out_size, void* d_ws, size_t ws_size,
                              hipStream_t stream) {
  (void)in_sizes; (void)n_in; (void)out_size;
  const float* x    = (const float*)d_in[0];
  const float* diag = (const float*)d_in[1];
  const float* u    = (const float*)d_in[2];
  float* y = (float*)d_out;
  char* wsb = (char*)d_ws;

  if (ws_size >= WS_NEED2) {
    short* part = (short*)wsb;                  // 134 MB
    float* ts   = (float*)(wsb + TS2_OFF);      // 8.36 MB
    k_proj3<<<NCH2,     256, 0, stream>>>(x, u, part);
    k_red3 <<<8160,     256, 0, stream>>>(part, ts);
    k_exp3 <<<NN / WIN2, 256, 0, stream>>>(x, diag, u, ts, y);
  } else {
    // fallback: proven three-launch path (464 us baseline)
    short* part = (short*)d_out;                // d_out doubles as scratch
    float* ts   = (float*)d_ws;
    k_proj2 <<<NCHUNK, 256, 0, stream>>>(x, u, part);
    k_reduce<<<8160,   256, 0, stream>>>(part, ts);
    k_exp2  <<<NN / WIN, 256, 0, stream>>>(x, diag, u, ts, y);
  }
}

// Round 8
// 500.383 us; speedup vs baseline: 3.5682x; 1.3919x over previous
//
#include <hip/hip_runtime.h>

// HODLR matvec, round 8: proven 3-launch baseline + bf16-u sidecar.
//   k_proj2b: baseline proj; while staging u it also writes ub = bf16(u) (ws).
//   k_reduce: baseline reduce (part -> ts), unchanged numerics.
//   k_exp2b : baseline exp but reads ub (half the bytes, zero conversion VALU
//             on the B-operand) and iterates levels 7..0 so recently-written
//             ub levels are LLC-resident.
// part lives in d_out (exact fit, proven). ub (268 MB) + ts in ws.

typedef __attribute__((ext_vector_type(8))) short bf16x8;
typedef __attribute__((ext_vector_type(4))) float f32x4;

constexpr int BATCH = 64;
constexpr int NN    = 262144;   // 2^18 nodes
constexpr int RANK  = 64;
constexpr int DEPTH = 8;
constexpr int CHUNK = 256;
constexpr int NCHUNK = NN / CHUNK;      // 1024
constexpr int LSTR  = 264;
constexpr int WIN   = 256;

// ws layout (bytes): ts | ub
constexpr size_t TS_BYTES = 510ull * 4096 * 4;            // 8,355,840
constexpr size_t UB_OFF   = 8388608;                      // 8 MB aligned
constexpr size_t UB_BYTES = (size_t)DEPTH * NN * RANK * 2; // 268,435,456
constexpr size_t WS_NEED  = UB_OFF + UB_BYTES;            // ~277 MB

__device__ __forceinline__ short f2bf(float f) {
  union { float f; unsigned u; } v; v.f = f;
  unsigned r = v.u + 0x7FFFu + ((v.u >> 16) & 1u);   // round-to-nearest-even
  return (short)(r >> 16);
}

__device__ __forceinline__ float bf2f(short s) {
  union { unsigned u; float f; } v; v.u = ((unsigned)(unsigned short)s) << 16;
  return v.f;
}

__device__ __forceinline__ bf16x8 pack8(f32x4 a, f32x4 b) {
  bf16x8 f;
  f[0] = f2bf(a[0]); f[1] = f2bf(a[1]); f[2] = f2bf(a[2]); f[3] = f2bf(a[3]);
  f[4] = f2bf(b[0]); f[5] = f2bf(b[1]); f[6] = f2bf(b[2]); f[7] = f2bf(b[3]);
  return f;
}

// ---------------- K1: projection + ub sidecar ----------------
// grid 1024 x 256 thr. LDS transposed u-tile (proven). While holding the fp32
// u row in registers, also emit the bf16 copy (8 dwordx4 stores / level).
__global__ __launch_bounds__(256, 4) void k_proj2b(
    const float* __restrict__ x, const float* __restrict__ u,
    short* __restrict__ part, unsigned short* __restrict__ ub)
{
  __shared__ alignas(16) short ulds[RANK * LSTR];   // 33,792 B

  const int c0   = blockIdx.x * CHUNK;
  const int tid  = threadIdx.x;
  const int w    = tid >> 6;
  const int lane = tid & 63;
  const int lg   = lane >> 4;
  const int lr   = lane & 15;

  bf16x8 xf[CHUNK / 32];
  {
    const float* xp = x + (size_t)(16 * w + lr) * NN + c0 + lg * 8;
    #pragma unroll
    for (int s = 0; s < CHUNK / 32; ++s) {
      f32x4 a = *(const f32x4*)(xp + s * 32);
      f32x4 b = *(const f32x4*)(xp + s * 32 + 4);
      xf[s] = pack8(a, b);
    }
  }

  for (int i = 0; i < DEPTH; ++i) {
    __syncthreads();   // previous level's MFMA reads done
    {
      const float* ug = u + ((size_t)i * NN + c0 + tid) * RANK;
      unsigned short* ur = ub + ((size_t)i * NN + c0 + tid) * RANK;
      short* col = &ulds[tid];
      #pragma unroll
      for (int h = 0; h < 2; ++h) {
        f32x4 t[8];
        #pragma unroll
        for (int q = 0; q < 8; ++q) t[q] = *(const f32x4*)(ug + h * 32 + q * 4);
        // bf16 sidecar: full row coverage, same f2bf rounding as LDS path
        #pragma unroll
        for (int m = 0; m < 4; ++m)
          *(bf16x8*)(ur + h * 32 + m * 8) = pack8(t[2 * m], t[2 * m + 1]);
        #pragma unroll
        for (int q = 0; q < 8; ++q) {
          #pragma unroll
          for (int e = 0; e < 4; ++e)
            col[(h * 32 + q * 4 + e) * LSTR] = f2bf(t[q][e]);
        }
      }
    }
    __syncthreads();

    f32x4 pacc[4];
    #pragma unroll
    for (int rt = 0; rt < 4; ++rt) pacc[rt] = (f32x4){0.f, 0.f, 0.f, 0.f};
    #pragma unroll
    for (int s = 0; s < CHUNK / 32; ++s) {
      #pragma unroll
      for (int rt = 0; rt < 4; ++rt) {
        bf16x8 bf = *(const bf16x8*)&ulds[(rt * 16 + lr) * LSTR + s * 32 + lg * 8];
        pacc[rt] = __builtin_amdgcn_mfma_f32_16x16x32_bf16(xf[s], bf, pacc[rt], 0, 0, 0);
      }
    }

    short* pb = part + ((size_t)i * NCHUNK + blockIdx.x) * (BATCH * RANK);
    #pragma unroll
    for (int rt = 0; rt < 4; ++rt) {
      #pragma unroll
      for (int v = 0; v < 4; ++v) {
        const int b = 16 * w + lg * 4 + v;
        pb[b * RANK + rt * 16 + lr] = f2bf(pacc[rt][v]);   // D: row=lg*4+v, col=lr
      }
    }
  }
}

// ---------------- KR: partial reduction -> ts fp32 (baseline) ----------------
__global__ __launch_bounds__(256, 4) void k_reduce(
    const short* __restrict__ part, float* __restrict__ ts)
{
  int g = blockIdx.x;
  int lvl = 0;
  while (g >= ((2 << lvl) * 16)) { g -= (2 << lvl) * 16; ++lvl; }
  const int block = g >> 4;
  const int bq = (g >> 2) & 3;
  const int rq = g & 3;
  const int contrib = 512 >> lvl;
  const int chunk0  = block * contrib;

  const int b = bq * 16 + (threadIdx.x >> 4);
  const int r = rq * 16 + (threadIdx.x & 15);

  const short* p = part + ((size_t)lvl * NCHUNK + chunk0) * (BATCH * RANK) + b * RANK + r;
  float s = 0.f;
  int k = 0;
  for (; k + 8 <= contrib; k += 8) {
    float a0 = bf2f(p[(size_t)(k + 0) * 4096]);
    float a1 = bf2f(p[(size_t)(k + 1) * 4096]);
    float a2 = bf2f(p[(size_t)(k + 2) * 4096]);
    float a3 = bf2f(p[(size_t)(k + 3) * 4096]);
    float a4 = bf2f(p[(size_t)(k + 4) * 4096]);
    float a5 = bf2f(p[(size_t)(k + 5) * 4096]);
    float a6 = bf2f(p[(size_t)(k + 6) * 4096]);
    float a7 = bf2f(p[(size_t)(k + 7) * 4096]);
    s += ((a0 + a1) + (a2 + a3)) + ((a4 + a5) + (a6 + a7));
  }
  for (; k < contrib; ++k) s += bf2f(p[(size_t)k * 4096]);

  const int off = (1 << (lvl + 1)) - 2;
  ts[(size_t)(off + block) * (BATCH * RANK) + b * RANK + r] = s;
}

// ---------------- K2: expansion from bf16 ub, levels 7..0 ----------------
// grid 1024 x 256 thr. B-operand = direct bf16x8 load (no conversion VALU,
// half the bytes of fp32 u). Reverse level order: ub_7.. most LLC-fresh.
__global__ __launch_bounds__(256, 4) void k_exp2b(
    const float* __restrict__ x, const float* __restrict__ diag,
    const unsigned short* __restrict__ ub, const float* __restrict__ ts,
    float* __restrict__ y)
{
  const int cw0  = blockIdx.x * WIN;
  const int tid  = threadIdx.x;
  const int w    = tid >> 6;
  const int lane = tid & 63;
  const int lg   = lane >> 4;
  const int lr   = lane & 15;
  const int bw   = 16 * w;

  f32x4 yacc[16];
  #pragma unroll
  for (int ct = 0; ct < 16; ++ct) yacc[ct] = (f32x4){0.f, 0.f, 0.f, 0.f};

  #pragma unroll
  for (int i = DEPTH - 1; i >= 0; --i) {
    const int blk = cw0 >> (17 - i);
    const int off = (1 << (i + 1)) - 2;
    const float* tb = ts + (size_t)(off + (blk ^ 1)) * (BATCH * RANK);

    // A fragments (t_sib): lane holds t[bw+lr][s2*32 + lg*8 + j]
    bf16x8 af[2];
    #pragma unroll
    for (int s2 = 0; s2 < 2; ++s2) {
      const float* p = tb + (size_t)(bw + lr) * RANK + s2 * 32 + lg * 8;
      af[s2] = pack8(*(const f32x4*)p, *(const f32x4*)(p + 4));
    }

    const unsigned short* ubl = ub + ((size_t)i * NN + cw0) * RANK;
    #pragma unroll
    for (int ct = 0; ct < 16; ++ct) {
      const unsigned short* up = ubl + (size_t)(ct * 16 + lr) * RANK + lg * 8;
      #pragma unroll
      for (int s2 = 0; s2 < 2; ++s2) {
        bf16x8 bf = *(const bf16x8*)(up + s2 * 32);
        yacc[ct] = __builtin_amdgcn_mfma_f32_16x16x32_bf16(af[s2], bf, yacc[ct], 0, 0, 0);
      }
    }
  }

  // epilogue: y = yacc + diag*x. D: col=lr (c), row=lg*4+v (b)
  #pragma unroll
  for (int ct = 0; ct < 16; ++ct) {
    const int c = cw0 + ct * 16 + lr;
    const float dg = diag[c];
    #pragma unroll
    for (int v = 0; v < 4; ++v) {
      const int b = bw + lg * 4 + v;
      const size_t idx = (size_t)b * NN + c;
      y[idx] = yacc[ct][v] + dg * x[idx];
    }
  }
}

// ================= legacy 3-kernel path (fallback only, proven 464 us) ======

__global__ __launch_bounds__(256, 4) void k_proj2(
    const float* __restrict__ x, const float* __restrict__ u,
    short* __restrict__ part)
{
  __shared__ alignas(16) short ulds[RANK * LSTR];

  const int c0   = blockIdx.x * CHUNK;
  const int tid  = threadIdx.x;
  const int w    = tid >> 6;
  const int lane = tid & 63;
  const int lg   = lane >> 4;
  const int lr   = lane & 15;

  bf16x8 xf[CHUNK / 32];
  {
    const float* xp = x + (size_t)(16 * w + lr) * NN + c0 + lg * 8;
    #pragma unroll
    for (int s = 0; s < CHUNK / 32; ++s) {
      f32x4 a = *(const f32x4*)(xp + s * 32);
      f32x4 b = *(const f32x4*)(xp + s * 32 + 4);
      xf[s] = pack8(a, b);
    }
  }

  for (int i = 0; i < DEPTH; ++i) {
    __syncthreads();
    {
      const float* ug = u + ((size_t)i * NN + c0 + tid) * RANK;
      short* col = &ulds[tid];
      #pragma unroll
      for (int h = 0; h < 2; ++h) {
        f32x4 t[8];
        #pragma unroll
        for (int q = 0; q < 8; ++q) t[q] = *(const f32x4*)(ug + h * 32 + q * 4);
        #pragma unroll
        for (int q = 0; q < 8; ++q) {
          #pragma unroll
          for (int e = 0; e < 4; ++e)
            col[(h * 32 + q * 4 + e) * LSTR] = f2bf(t[q][e]);
        }
      }
    }
    __syncthreads();

    f32x4 pacc[4];
    #pragma unroll
    for (int rt = 0; rt < 4; ++rt) pacc[rt] = (f32x4){0.f, 0.f, 0.f, 0.f};
    #pragma unroll
    for (int s = 0; s < CHUNK / 32; ++s) {
      #pragma unroll
      for (int rt = 0; rt < 4; ++rt) {
        bf16x8 bf = *(const bf16x8*)&ulds[(rt * 16 + lr) * LSTR + s * 32 + lg * 8];
        pacc[rt] = __builtin_amdgcn_mfma_f32_16x16x32_bf16(xf[s], bf, pacc[rt], 0, 0, 0);
      }
    }

    short* pb = part + ((size_t)i * NCHUNK + blockIdx.x) * (BATCH * RANK);
    #pragma unroll
    for (int rt = 0; rt < 4; ++rt) {
      #pragma unroll
      for (int v = 0; v < 4; ++v) {
        const int b = 16 * w + lg * 4 + v;
        pb[b * RANK + rt * 16 + lr] = f2bf(pacc[rt][v]);
      }
    }
  }
}

__global__ __launch_bounds__(256, 4) void k_exp2(
    const float* __restrict__ x, const float* __restrict__ diag,
    const float* __restrict__ u, const float* __restrict__ ts,
    float* __restrict__ y)
{
  const int cw0  = blockIdx.x * WIN;
  const int tid  = threadIdx.x;
  const int w    = tid >> 6;
  const int lane = tid & 63;
  const int lg   = lane >> 4;
  const int lr   = lane & 15;
  const int bw   = 16 * w;

  f32x4 yacc[16];
  #pragma unroll
  for (int ct = 0; ct < 16; ++ct) yacc[ct] = (f32x4){0.f, 0.f, 0.f, 0.f};

  #pragma unroll
  for (int i = 0; i < DEPTH; ++i) {
    const int blk = cw0 >> (17 - i);
    const int off = (1 << (i + 1)) - 2;
    const float* tb = ts + (size_t)(off + (blk ^ 1)) * (BATCH * RANK);

    bf16x8 af[2];
    #pragma unroll
    for (int s2 = 0; s2 < 2; ++s2) {
      const float* p = tb + (size_t)(bw + lr) * RANK + s2 * 32 + lg * 8;
      af[s2] = pack8(*(const f32x4*)p, *(const f32x4*)(p + 4));
    }

    const float* ubp = u + ((size_t)i * NN + cw0) * RANK;
    #pragma unroll
    for (int ct = 0; ct < 16; ++ct) {
      const float* up = ubp + (size_t)(ct * 16 + lr) * RANK + lg * 8;
      #pragma unroll
      for (int s2 = 0; s2 < 2; ++s2) {
        f32x4 a = *(const f32x4*)(up + s2 * 32);
        f32x4 b = *(const f32x4*)(up + s2 * 32 + 4);
        yacc[ct] = __builtin_amdgcn_mfma_f32_16x16x32_bf16(af[s2], pack8(a, b), yacc[ct], 0, 0, 0);
      }
    }
  }

  #pragma unroll
  for (int ct = 0; ct < 16; ++ct) {
    const int c = cw0 + ct * 16 + lr;
    const float dg = diag[c];
    #pragma unroll
    for (int v = 0; v < 4; ++v) {
      const int b = bw + lg * 4 + v;
      const size_t idx = (size_t)b * NN + c;
      y[idx] = yacc[ct][v] + dg * x[idx];
    }
  }
}

extern "C" void kernel_launch(void* const* d_in, const int* in_sizes, int n_in,
                              void* d_out, int out_size, void* d_ws, size_t ws_size,
                              hipStream_t stream) {
  (void)in_sizes; (void)n_in; (void)out_size;
  const float* x    = (const float*)d_in[0];
  const float* diag = (const float*)d_in[1];
  const float* u    = (const float*)d_in[2];
  float* y    = (float*)d_out;
  short* part = (short*)d_out;          // d_out doubles as partial scratch (exact fit)
  char* wsb   = (char*)d_ws;
  float* ts   = (float*)wsb;

  if (ws_size >= WS_NEED) {
    unsigned short* ub = (unsigned short*)(wsb + UB_OFF);   // 268 MB bf16 u
    k_proj2b<<<NCHUNK, 256, 0, stream>>>(x, u, part, ub);
    k_reduce<<<8160,   256, 0, stream>>>(part, ts);
    k_exp2b <<<NN / WIN, 256, 0, stream>>>(x, diag, ub, ts, y);
  } else {
    // fallback: proven three-launch path (464 us baseline)
    k_proj2 <<<NCHUNK, 256, 0, stream>>>(x, u, part);
    k_reduce<<<8160,   256, 0, stream>>>(part, ts);
    k_exp2  <<<NN / WIN, 256, 0, stream>>>(x, diag, u, ts, y);
  }
}